// Round 8
// baseline (86.365 us; speedup 1.0000x reference)
//
#include <hip/hip_runtime.h>
#include <hip/hip_bf16.h>

#define LL 128
#define DD 256
#define PP 1024
#define TU_C 86400
#define TB_C 3600
#define NEGF -4294967296.0f   // float(-2**32+1) rounds to -2^32

// NOTE: parameter names must not collide with .x/.y/.z/.w member tokens
#define FMA4(ACC_, SS_, WW_) { (ACC_).x += (SS_)*(WW_).x; (ACC_).y += (SS_)*(WW_).y; (ACC_).z += (SS_)*(WW_).z; (ACC_).w += (SS_)*(WW_).w; }
#define ADD4(ACC_, WW_) { (ACC_).x += (WW_).x; (ACC_).y += (WW_).y; (ACC_).z += (WW_).z; (ACC_).w += (WW_).w; }

__device__ __forceinline__ float wredSum(float v) {
#pragma unroll
  for (int o = 32; o; o >>= 1) v += __shfl_xor(v, o);
  return v;
}
__device__ __forceinline__ float wredMax(float v) {
#pragma unroll
  for (int o = 32; o; o >>= 1) v = fmaxf(v, __shfl_xor(v, o));
  return v;
}

// ---------------------------------------------------------------------------
// Kernel 0: transpose all weight matrices so GEMMs read coalesced.
// WT layout: WTq 0, WTk 65536, WTv 131072, WTf1 196608, WTf2 262144,
// WTdec 327680 (262144). 32x32 tiles, 576 blocks.
// ---------------------------------------------------------------------------
__global__ __launch_bounds__(256) void k_wt(
    const float* __restrict__ wq, const float* __restrict__ wk,
    const float* __restrict__ wv, const float* __restrict__ wf1,
    const float* __restrict__ wf2, const float* __restrict__ wdec,
    float* __restrict__ wt)
{
  __shared__ float s[32][33];
  const int tile = blockIdx.x;
  const float* src; float* dst; int R, m;
  if (tile < 320) {
    const int mi = tile >> 6; m = tile & 63;
    src = (mi == 0) ? wq : (mi == 1) ? wk : (mi == 2) ? wv : (mi == 3) ? wf1 : wf2;
    dst = wt + mi * 65536; R = 256;
  } else {
    m = tile - 320; src = wdec; dst = wt + 327680; R = 1024;
  }
  const int sr = (m >> 3) * 32, sc0 = (m & 7) * 32;
  const int tx = threadIdx.x & 31, ty = threadIdx.x >> 5;
#pragma unroll
  for (int i = 0; i < 4; ++i)
    s[ty + 8 * i][tx] = src[(sr + ty + 8 * i) * 256 + sc0 + tx];
  __syncthreads();
#pragma unroll
  for (int i = 0; i < 4; ++i)
    dst[(sc0 + ty + 8 * i) * R + sr + tx] = s[tx][ty + 8 * i];
}

// ---------------------------------------------------------------------------
// Kernel 1: Q/K/V projections. grid (64 row-tiles of 8, 3), 512 threads
// (8 waves -> TLP). Thread = 1 row x 4 cols, 4 accumulators (chain/4).
// K written TRANSPOSED per batch: KT[b][e][k].
// ---------------------------------------------------------------------------
__global__ __launch_bounds__(512) void k_qkv(
    const float* __restrict__ src, const float* __restrict__ wt,
    const float* __restrict__ bq, const float* __restrict__ bk,
    const float* __restrict__ bv,
    float* __restrict__ Q, float* __restrict__ KT, float* __restrict__ V)
{
  __shared__ float xs[8][DD];
  const int t = threadIdx.x, cg = t & 63, rg = t >> 6;   // 8 rows, 64 colgroups
  const int r0 = blockIdx.x * 8;
  const int mat = blockIdx.y;
  const float* w = wt + mat * 65536;
  const float* bi = (mat == 0) ? bq : (mat == 1) ? bk : bv;
  for (int i = t; i < 8 * DD; i += 512) xs[i >> 8][i & 255] = src[r0 * DD + i];
  __syncthreads();
  float4 a0 = *(const float4*)(bi + 4 * cg);
  float4 a1 = {0.f,0.f,0.f,0.f}, a2 = {0.f,0.f,0.f,0.f}, a3 = {0.f,0.f,0.f,0.f};
  for (int e = 0; e < DD; e += 4) {
    const float4 xa = *(const float4*)&xs[rg][e];
    const float* wp = w + e * DD + 4 * cg;
    FMA4(a0, xa.x, *(const float4*)(wp))
    FMA4(a1, xa.y, *(const float4*)(wp + DD))
    FMA4(a2, xa.z, *(const float4*)(wp + 2 * DD))
    FMA4(a3, xa.w, *(const float4*)(wp + 3 * DD))
  }
  a0.x = (a0.x + a1.x) + (a2.x + a3.x);
  a0.y = (a0.y + a1.y) + (a2.y + a3.y);
  a0.z = (a0.z + a1.z) + (a2.z + a3.z);
  a0.w = (a0.w + a1.w) + (a2.w + a3.w);
  const int r = r0 + rg;
  if (mat == 1) {
    const int bA = r >> 7, kA = r & 127;
    KT[bA * 32768 + (4 * cg + 0) * 128 + kA] = a0.x;
    KT[bA * 32768 + (4 * cg + 1) * 128 + kA] = a0.y;
    KT[bA * 32768 + (4 * cg + 2) * 128 + kA] = a0.z;
    KT[bA * 32768 + (4 * cg + 3) * 128 + kA] = a0.w;
  } else {
    float* o = (mat == 0) ? Q : V;
    *(float4*)(o + r * DD + 4 * cg) = a0;
  }
}

// ---------------------------------------------------------------------------
// Kernel 2: attention scores+softmax+weighted hist. grid 512=(b,j), 192 thr.
// Waves 0-1: K-dot via KT (4-acc ILP). Wave 2: 34 embedding dots (4-acc).
// ---------------------------------------------------------------------------
__global__ __launch_bounds__(192) void k_attnA(
    const float* __restrict__ Q, const float* __restrict__ KT,
    const float* __restrict__ hour_emb, const float* __restrict__ day_emb,
    const int* __restrict__ seq_lens, const int* __restrict__ ts_g,
    float* __restrict__ Sout, float* __restrict__ WHout)
{
  const int b = blockIdx.x >> 7;
  const int j = blockIdx.x & (LL - 1);
  const int t = threadIdx.x;
  __shared__ float qrow[DD];
  __shared__ float qhd[34];
  __shared__ float whd[34];
  __shared__ float red[8];
  const int row = b * LL + j;
  for (int i = t; i < DD; i += 192) qrow[i] = Q[row * DD + i];
  if (t < 34) whd[t] = 0.f;
  __syncthreads();
  float kdot = 0.f;
  if (t < LL) {
    const float* ktb = KT + b * 32768;
    float4 kd = {0.f,0.f,0.f,0.f};
#pragma unroll 8
    for (int e = 0; e < DD; e += 4) {
      const float4 q4 = *(const float4*)&qrow[e];
      const float* kp = ktb + e * LL + t;
      kd.x += q4.x * kp[0];
      kd.y += q4.y * kp[128];
      kd.z += q4.z * kp[256];
      kd.w += q4.w * kp[384];
    }
    kdot = (kd.x + kd.y) + (kd.z + kd.w);
  } else if (t < 162) {
    const int i = t - 128;
    const float* emb = (i < 26) ? (hour_emb + i * DD) : (day_emb + (i - 26) * DD);
    float4 ed = {0.f,0.f,0.f,0.f};
    for (int e = 0; e < DD; e += 4) {
      const float4 q4 = *(const float4*)&qrow[e];
      const float4 e4 = *(const float4*)(emb + e);
      ed.x += q4.x * e4.x; ed.y += q4.y * e4.y;
      ed.z += q4.z * e4.z; ed.w += q4.w * e4.w;
    }
    qhd[i] = (ed.x + ed.y) + (ed.z + ed.w);
  }
  const int len = seq_lens[b];
  const int* ts = ts_g + b * LL;
  const int tj = ts[j];
  __syncthreads();  // qhd ready
  int hidx = 0, didx = 0;
  float s = NEGF;
  const bool valid = (t < LL) && (j < len) && (t <= j);
  if (valid) {
    const int diff = tj - ts[t];                       // >= 0 (ts sorted, t<=j)
    hidx = (j == b) ? 1 : ((diff % TU_C) / TB_C + 2);  // faithful j==b bug
    didx = min(diff / TU_C + 1, 7);
    s = (kdot + qhd[hidx] + qhd[26 + didx]) * 0.0625f; // /sqrt(256)
  }
  // softmax over k=0..127 (all-NEG rows -> uniform 1/128, like reference)
  float mv = (t < LL) ? s : -3.4e38f;
  mv = wredMax(mv);
  if ((t & 63) == 0) red[t >> 6] = mv;
  __syncthreads();
  const float m = fmaxf(red[0], red[1]);
  const float p = (t < LL) ? expf(s - m) : 0.f;
  const float sv = wredSum(p);
  if ((t & 63) == 0) red[4 + (t >> 6)] = sv;
  __syncthreads();
  const float Z = red[4] + red[5];
  if (t < LL) {
    const float aw = p / Z;
    Sout[row * LL + t] = aw;
    atomicAdd(&whd[hidx], aw);       // idx 0 -> zero embedding row: harmless
    atomicAdd(&whd[26 + didx], aw);
  }
  __syncthreads();
  if (t < 34) WHout[row * 34 + t] = whd[t];
}

// ---------------------------------------------------------------------------
// Kernel 3: fused (aw@V + hist@emb + residual + LN1) + FFN + LN2 -> F.
// grid 512 = (b,j): ONE row per block, 4 waves split k/e quarters, LDS
// combine. 2x the blocks of round-7 (TLP), chains quartered.
// ---------------------------------------------------------------------------
__global__ __launch_bounds__(256) void k_attnF(
    const float* __restrict__ Sin, const float* __restrict__ WHin,
    const float* __restrict__ Vm, const float* __restrict__ src,
    const float* __restrict__ hour_emb, const float* __restrict__ day_emb,
    const float* __restrict__ g11, const float* __restrict__ b11,
    const float* __restrict__ wt1, const float* __restrict__ bf1,
    const float* __restrict__ wt2, const float* __restrict__ bf2,
    const float* __restrict__ g12, const float* __restrict__ b12,
    float* __restrict__ F)
{
  const int b = blockIdx.x >> 7;
  const int j = blockIdx.x & (LL - 1);
  const int t = threadIdx.x;
  const int w = t >> 6, lane = t & 63;
  const int col = 4 * lane;
  __shared__ float ss[LL];
  __shared__ float wh[34];
  __shared__ float xs[DD];
  __shared__ float hs[DD];
  __shared__ float ps[4][DD];
  const int row = b * LL + j;
  if (t < LL) ss[t] = Sin[row * LL + t];
  else if (t < LL + 34) wh[t - LL] = WHin[row * 34 + t - LL];
  __syncthreads();
  // ---- Phase 1: partial aw@V over k-quarter + emb/src on waves 0/1 ----
  float4 aA = {0.f,0.f,0.f,0.f}, aB = {0.f,0.f,0.f,0.f};
  {
    const float* vb = Vm + b * LL * DD + col;
    const int k0 = 32 * w;
#pragma unroll 8
    for (int kk = 0; kk < 32; kk += 2) {
      FMA4(aA, ss[k0 + kk],     *(const float4*)(vb + (k0 + kk) * DD))
      FMA4(aB, ss[k0 + kk + 1], *(const float4*)(vb + (k0 + kk + 1) * DD))
    }
  }
  float4 a;
  a.x = aA.x + aB.x; a.y = aA.y + aB.y; a.z = aA.z + aB.z; a.w = aA.w + aB.w;
  if (w == 0) {
#pragma unroll
    for (int i = 0; i < 26; ++i)
      FMA4(a, wh[i], *(const float4*)(hour_emb + i * DD + col))
  } else if (w == 1) {
#pragma unroll
    for (int i = 0; i < 8; ++i)
      FMA4(a, wh[26 + i], *(const float4*)(day_emb + i * DD + col))
    const float4 s4 = *(const float4*)(src + row * DD + col);
    ADD4(a, s4)
  }
  *(float4*)&ps[w][col] = a;
  __syncthreads();
  if (w == 0) {   // combine + LN1 (wave 0's 64 lanes x 4 cols = all 256)
    float4 x = a;
    const float4 p1 = *(const float4*)&ps[1][col];
    const float4 p2 = *(const float4*)&ps[2][col];
    const float4 p3 = *(const float4*)&ps[3][col];
    x.x = (x.x + p1.x) + (p2.x + p3.x); x.y = (x.y + p1.y) + (p2.y + p3.y);
    x.z = (x.z + p1.z) + (p2.z + p3.z); x.w = (x.w + p1.w) + (p2.w + p3.w);
    const float sm = wredSum(x.x + x.y + x.z + x.w);
    const float sq = wredSum(x.x*x.x + x.y*x.y + x.z*x.z + x.w*x.w);
    const float mean = sm * (1.f / DD);
    const float rstd = rsqrtf(sq * (1.f / DD) - mean * mean + 1e-5f);
    const float4 g4 = *(const float4*)(g11 + col);
    const float4 b4 = *(const float4*)(b11 + col);
    x.x = (x.x - mean) * rstd * g4.x + b4.x;
    x.y = (x.y - mean) * rstd * g4.y + b4.y;
    x.z = (x.z - mean) * rstd * g4.z + b4.z;
    x.w = (x.w - mean) * rstd * g4.w + b4.w;
    *(float4*)&xs[col] = x;
  }
  __syncthreads();
  // ---- Phase 2: H = relu(x @ W1^T + b1), e-quarter, 4 accs ----
  {
    float4 h0 = {0.f,0.f,0.f,0.f}, h1 = {0.f,0.f,0.f,0.f};
    float4 h2 = {0.f,0.f,0.f,0.f}, h3 = {0.f,0.f,0.f,0.f};
    const int e0 = 64 * w;
    for (int e = e0; e < e0 + 64; e += 4) {
      const float4 xa = *(const float4*)&xs[e];
      const float* wp = wt1 + e * DD + col;
      FMA4(h0, xa.x, *(const float4*)(wp))
      FMA4(h1, xa.y, *(const float4*)(wp + DD))
      FMA4(h2, xa.z, *(const float4*)(wp + 2 * DD))
      FMA4(h3, xa.w, *(const float4*)(wp + 3 * DD))
    }
    h0.x = (h0.x + h1.x) + (h2.x + h3.x); h0.y = (h0.y + h1.y) + (h2.y + h3.y);
    h0.z = (h0.z + h1.z) + (h2.z + h3.z); h0.w = (h0.w + h1.w) + (h2.w + h3.w);
    *(float4*)&ps[w][col] = h0;
  }
  __syncthreads();
  if (w == 1) {   // combine + bias + relu
    float4 hv = *(const float4*)&ps[0][col];
    const float4 p1 = *(const float4*)&ps[1][col];
    const float4 p2 = *(const float4*)&ps[2][col];
    const float4 p3 = *(const float4*)&ps[3][col];
    const float4 bb = *(const float4*)(bf1 + col);
    hv.x = fmaxf((hv.x + p1.x) + (p2.x + p3.x) + bb.x, 0.f);
    hv.y = fmaxf((hv.y + p1.y) + (p2.y + p3.y) + bb.y, 0.f);
    hv.z = fmaxf((hv.z + p1.z) + (p2.z + p3.z) + bb.z, 0.f);
    hv.w = fmaxf((hv.w + p1.w) + (p2.w + p3.w) + bb.w, 0.f);
    *(float4*)&hs[col] = hv;
  }
  __syncthreads();
  // ---- Phase 3: F = LN2(H @ W2^T + b2 + x), e-quarter, 4 accs ----
  {
    float4 o0 = {0.f,0.f,0.f,0.f}, o1 = {0.f,0.f,0.f,0.f};
    float4 o2 = {0.f,0.f,0.f,0.f}, o3 = {0.f,0.f,0.f,0.f};
    const int e0 = 64 * w;
    for (int e = e0; e < e0 + 64; e += 4) {
      const float4 xa = *(const float4*)&hs[e];
      const float* wp = wt2 + e * DD + col;
      FMA4(o0, xa.x, *(const float4*)(wp))
      FMA4(o1, xa.y, *(const float4*)(wp + DD))
      FMA4(o2, xa.z, *(const float4*)(wp + 2 * DD))
      FMA4(o3, xa.w, *(const float4*)(wp + 3 * DD))
    }
    o0.x = (o0.x + o1.x) + (o2.x + o3.x); o0.y = (o0.y + o1.y) + (o2.y + o3.y);
    o0.z = (o0.z + o1.z) + (o2.z + o3.z); o0.w = (o0.w + o1.w) + (o2.w + o3.w);
    *(float4*)&ps[w][col] = o0;
  }
  __syncthreads();
  if (w == 0) {   // combine + bias + residual + LN2 + store
    float4 x = *(const float4*)&ps[0][col];
    const float4 p1 = *(const float4*)&ps[1][col];
    const float4 p2 = *(const float4*)&ps[2][col];
    const float4 p3 = *(const float4*)&ps[3][col];
    const float4 bb = *(const float4*)(bf2 + col);
    const float4 xr = *(const float4*)&xs[col];
    x.x = (x.x + p1.x) + (p2.x + p3.x) + bb.x + xr.x;
    x.y = (x.y + p1.y) + (p2.y + p3.y) + bb.y + xr.y;
    x.z = (x.z + p1.z) + (p2.z + p3.z) + bb.z + xr.z;
    x.w = (x.w + p1.w) + (p2.w + p3.w) + bb.w + xr.w;
    const float sm = wredSum(x.x + x.y + x.z + x.w);
    const float sq = wredSum(x.x*x.x + x.y*x.y + x.z*x.z + x.w*x.w);
    const float mean = sm * (1.f / DD);
    const float rstd = rsqrtf(sq * (1.f / DD) - mean * mean + 1e-5f);
    const float4 g4 = *(const float4*)(g12 + col);
    const float4 b4 = *(const float4*)(b12 + col);
    x.x = (x.x - mean) * rstd * g4.x + b4.x;
    x.y = (x.y - mean) * rstd * g4.y + b4.y;
    x.z = (x.z - mean) * rstd * g4.z + b4.z;
    x.w = (x.w - mean) * rstd * g4.w + b4.w;
    *(float4*)(F + row * DD + col) = x;
  }
}

// ---------------------------------------------------------------------------
// Kernel 4: GS[b,j] = (prefix-sum F[k<=j] + label-emb)/(j+1). grid 512=(b,j),
// 256 thr (d). Direct prefix with 4 accumulators (independent loads, MLP).
// Absorbs old k_tsum (one fewer launch).
// ---------------------------------------------------------------------------
__global__ __launch_bounds__(256) void k_prep2(
    const float* __restrict__ F,
    const float* __restrict__ hour_emb, const float* __restrict__ day_emb,
    const int* __restrict__ seq_lens, const int* __restrict__ ts_g,
    const int* __restrict__ lts_g,
    float* __restrict__ GS)
{
  const int b = blockIdx.x >> 7;
  const int j = blockIdx.x & (LL - 1);
  const int t = threadIdx.x;
  __shared__ float cnt[34];
  if (t < 34) cnt[t] = 0.f;
  __syncthreads();
  const int len = seq_lens[b];
  if (t < LL && t <= j && j < len) {     // valid; no j==b override for labels
    const int ldiff = lts_g[b * LL + j] - ts_g[b * LL + t];   // >= 0
    atomicAdd(&cnt[(ldiff % TU_C) / TB_C + 2], 1.f);
    atomicAdd(&cnt[26 + min(ldiff / TU_C + 1, 7)], 1.f);
  }
  __syncthreads();
  const float* fb = F + b * LL * DD + t;
  float A0 = 0.f, A1 = 0.f, A2 = 0.f, A3 = 0.f;
  int k = 0;
  for (; k + 4 <= j + 1; k += 4) {
    A0 += fb[(k + 0) * DD];
    A1 += fb[(k + 1) * DD];
    A2 += fb[(k + 2) * DD];
    A3 += fb[(k + 3) * DD];
  }
  float gacc = (A0 + A1) + (A2 + A3);
  for (; k <= j; ++k) gacc += fb[k * DD];
  float sv0 = 0.f, sv1 = 0.f;
#pragma unroll
  for (int i = 0; i < 26; i += 2) {
    sv0 += cnt[i] * hour_emb[i * DD + t];
    sv1 += cnt[i + 1] * hour_emb[(i + 1) * DD + t];
  }
#pragma unroll
  for (int i = 0; i < 8; i += 2) {
    sv0 += cnt[26 + i] * day_emb[i * DD + t];
    sv1 += cnt[27 + i] * day_emb[(i + 1) * DD + t];
  }
  GS[(b * LL + j) * DD + t] = (gacc + sv0 + sv1) / (float)(j + 1);
}

// ---------------------------------------------------------------------------
// Kernel 5: decoder GEMM pooled = GS @ WTdec + bdec.
// grid (4 col-tiles of 256, 64 row-tiles of 8), 512 threads (8 waves).
// Thread = 1 row x 4 cols, 4 accumulators. Coalesced 1KB weight lines/wave.
// ---------------------------------------------------------------------------
__global__ __launch_bounds__(512) void k_dec(
    const float* __restrict__ GS, const float* __restrict__ wtd,
    const float* __restrict__ bdec, float* __restrict__ out)
{
  __shared__ float xs[8][DD];
  const int t = threadIdx.x, cg = t & 63, rg = t >> 6;
  const int c0 = blockIdx.x * 256;
  const int r0 = blockIdx.y * 8;
  for (int i = t; i < 8 * DD; i += 512) xs[i >> 8][i & 255] = GS[r0 * DD + i];
  __syncthreads();
  const int col = c0 + 4 * cg;
  float4 a0 = *(const float4*)(bdec + col);
  float4 a1 = {0.f,0.f,0.f,0.f}, a2 = {0.f,0.f,0.f,0.f}, a3 = {0.f,0.f,0.f,0.f};
  for (int e = 0; e < DD; e += 4) {
    const float* wp = wtd + e * PP + col;
    FMA4(a0, xs[rg][e],     *(const float4*)(wp))
    FMA4(a1, xs[rg][e + 1], *(const float4*)(wp + PP))
    FMA4(a2, xs[rg][e + 2], *(const float4*)(wp + 2 * PP))
    FMA4(a3, xs[rg][e + 3], *(const float4*)(wp + 3 * PP))
  }
  a0.x = (a0.x + a1.x) + (a2.x + a3.x);
  a0.y = (a0.y + a1.y) + (a2.y + a3.y);
  a0.z = (a0.z + a1.z) + (a2.z + a3.z);
  a0.w = (a0.w + a1.w) + (a2.w + a3.w);
  *(float4*)(out + (r0 + rg) * PP + col) = a0;
}

extern "C" void kernel_launch(void* const* d_in, const int* in_sizes, int n_in,
                              void* d_out, int out_size, void* d_ws, size_t ws_size,
                              hipStream_t stream)
{
  (void)in_sizes; (void)n_in; (void)out_size; (void)ws_size;
  const float* src      = (const float*)d_in[0];
  const float* hour_emb = (const float*)d_in[1];
  const float* day_emb  = (const float*)d_in[2];
  const float* wq  = (const float*)d_in[3];
  const float* bq  = (const float*)d_in[4];
  const float* wk  = (const float*)d_in[5];
  const float* bk  = (const float*)d_in[6];
  const float* wv  = (const float*)d_in[7];
  const float* bv  = (const float*)d_in[8];
  const float* g11 = (const float*)d_in[9];
  const float* b11 = (const float*)d_in[10];
  const float* wf1 = (const float*)d_in[11];
  const float* bf1 = (const float*)d_in[12];
  const float* wf2 = (const float*)d_in[13];
  const float* bf2 = (const float*)d_in[14];
  const float* g12 = (const float*)d_in[15];
  const float* b12 = (const float*)d_in[16];
  const float* wdec = (const float*)d_in[17];
  const float* bdec = (const float*)d_in[18];
  const int* seq_lens = (const int*)d_in[19];
  const int* ts  = (const int*)d_in[20];
  const int* lts = (const int*)d_in[21];
  float* out = (float*)d_out;
  float* ws = (float*)d_ws;
  // ws layout (floats):
  float* WT  = ws;                  // 589824 (5x65536 + 262144)
  float* Q   = ws + 589824;         // 131072
  float* KT  = ws + 720896;         // 131072 (4 x [256e][128k])
  float* V   = ws + 851968;         // 131072
  float* F   = ws + 983040;         // 131072
  float* GS  = ws + 1114112;        // 131072
  float* S   = ws + 1245184;        // 65536  (512 x 128 attention rows)
  float* WH  = ws + 1310720;        // 17408  (512 x 34 weighted hists)

  k_wt   <<<576, 256, 0, stream>>>(wq, wk, wv, wf1, wf2, wdec, WT);
  k_qkv  <<<dim3(64, 3), 512, 0, stream>>>(src, WT, bq, bk, bv, Q, KT, V);
  k_attnA<<<512, 192, 0, stream>>>(Q, KT, hour_emb, day_emb, seq_lens, ts, S, WH);
  k_attnF<<<512, 256, 0, stream>>>(S, WH, V, src, hour_emb, day_emb, g11, b11,
                                   WT + 196608, bf1, WT + 262144, bf2, g12, b12, F);
  k_prep2<<<512, 256, 0, stream>>>(F, hour_emb, day_emb, seq_lens, ts, lts, GS);
  k_dec  <<<dim3(4, 64), 512, 0, stream>>>(GS, WT + 327680, bdec, out);
}

// Round 9
// 81.890 us; speedup vs baseline: 1.0546x; 1.0546x over previous
//
#include <hip/hip_runtime.h>
#include <hip/hip_bf16.h>

#define LL 128
#define DD 256
#define PP 1024
#define TU_C 86400
#define TB_C 3600
#define NEGF -4294967296.0f   // float(-2**32+1) rounds to -2^32

// NOTE: parameter names must not collide with .x/.y/.z/.w member tokens
#define FMA4(ACC_, SS_, WW_) { (ACC_).x += (SS_)*(WW_).x; (ACC_).y += (SS_)*(WW_).y; (ACC_).z += (SS_)*(WW_).z; (ACC_).w += (SS_)*(WW_).w; }
#define ADD4(ACC_, WW_) { (ACC_).x += (WW_).x; (ACC_).y += (WW_).y; (ACC_).z += (WW_).z; (ACC_).w += (WW_).w; }

__device__ __forceinline__ float wredSum(float v) {
#pragma unroll
  for (int o = 32; o; o >>= 1) v += __shfl_xor(v, o);
  return v;
}
__device__ __forceinline__ float wredMax(float v) {
#pragma unroll
  for (int o = 32; o; o >>= 1) v = fmaxf(v, __shfl_xor(v, o));
  return v;
}

// ---------------------------------------------------------------------------
// Kernel 0: transpose weights. WT: WTq 0, WTk 65536, WTv 131072, WTf1 196608,
// WTf2 262144, WTdec 327680. 32x32 tiles, 576 blocks. (proven)
// ---------------------------------------------------------------------------
__global__ __launch_bounds__(256) void k_wt(
    const float* __restrict__ wq, const float* __restrict__ wk,
    const float* __restrict__ wv, const float* __restrict__ wf1,
    const float* __restrict__ wf2, const float* __restrict__ wdec,
    float* __restrict__ wt)
{
  __shared__ float s[32][33];
  const int tile = blockIdx.x;
  const float* src; float* dst; int R, m;
  if (tile < 320) {
    const int mi = tile >> 6; m = tile & 63;
    src = (mi == 0) ? wq : (mi == 1) ? wk : (mi == 2) ? wv : (mi == 3) ? wf1 : wf2;
    dst = wt + mi * 65536; R = 256;
  } else {
    m = tile - 320; src = wdec; dst = wt + 327680; R = 1024;
  }
  const int sr = (m >> 3) * 32, sc0 = (m & 7) * 32;
  const int tx = threadIdx.x & 31, ty = threadIdx.x >> 5;
#pragma unroll
  for (int i = 0; i < 4; ++i)
    s[ty + 8 * i][tx] = src[(sr + ty + 8 * i) * 256 + sc0 + tx];
  __syncthreads();
#pragma unroll
  for (int i = 0; i < 4; ++i)
    dst[(sc0 + ty + 8 * i) * R + sr + tx] = s[tx][ty + 8 * i];
}

// ---------------------------------------------------------------------------
// Kernel 1: Q/K/V projections. grid (64,3), 512 thr. (proven round-8)
// K written TRANSPOSED per batch: KT[b][e][k].
// ---------------------------------------------------------------------------
__global__ __launch_bounds__(512) void k_qkv(
    const float* __restrict__ src, const float* __restrict__ wt,
    const float* __restrict__ bq, const float* __restrict__ bk,
    const float* __restrict__ bv,
    float* __restrict__ Q, float* __restrict__ KT, float* __restrict__ V)
{
  __shared__ float xs[8][DD];
  const int t = threadIdx.x, cg = t & 63, rg = t >> 6;
  const int r0 = blockIdx.x * 8;
  const int mat = blockIdx.y;
  const float* w = wt + mat * 65536;
  const float* bi = (mat == 0) ? bq : (mat == 1) ? bk : bv;
  for (int i = t; i < 8 * DD; i += 512) xs[i >> 8][i & 255] = src[r0 * DD + i];
  __syncthreads();
  float4 a0 = *(const float4*)(bi + 4 * cg);
  float4 a1 = {0.f,0.f,0.f,0.f}, a2 = {0.f,0.f,0.f,0.f}, a3 = {0.f,0.f,0.f,0.f};
  for (int e = 0; e < DD; e += 4) {
    const float4 xa = *(const float4*)&xs[rg][e];
    const float* wp = w + e * DD + 4 * cg;
    FMA4(a0, xa.x, *(const float4*)(wp))
    FMA4(a1, xa.y, *(const float4*)(wp + DD))
    FMA4(a2, xa.z, *(const float4*)(wp + 2 * DD))
    FMA4(a3, xa.w, *(const float4*)(wp + 3 * DD))
  }
  a0.x = (a0.x + a1.x) + (a2.x + a3.x);
  a0.y = (a0.y + a1.y) + (a2.y + a3.y);
  a0.z = (a0.z + a1.z) + (a2.z + a3.z);
  a0.w = (a0.w + a1.w) + (a2.w + a3.w);
  const int r = r0 + rg;
  if (mat == 1) {
    const int bA = r >> 7, kA = r & 127;
    KT[bA * 32768 + (4 * cg + 0) * 128 + kA] = a0.x;
    KT[bA * 32768 + (4 * cg + 1) * 128 + kA] = a0.y;
    KT[bA * 32768 + (4 * cg + 2) * 128 + kA] = a0.z;
    KT[bA * 32768 + (4 * cg + 3) * 128 + kA] = a0.w;
  } else {
    float* o = (mat == 0) ? Q : V;
    *(float4*)(o + r * DD + 4 * cg) = a0;
  }
}

// ---------------------------------------------------------------------------
// Kernel 2: FUSED attention + FFN. grid 128 = (b, 32 j-tiles of 4), 256 thr.
// Wave w owns row j0+w for scores/softmax/LN (shuffle-only). aw@V and FFN
// GEMMs are quarter-split across waves with all 4 rows shared per weight
// read (transposed LDS operands -> ds_read_b128 feeds 16 FMAs).
// ---------------------------------------------------------------------------
__global__ __launch_bounds__(256) void k_attn(
    const float* __restrict__ Q, const float* __restrict__ KT,
    const float* __restrict__ Vm, const float* __restrict__ src,
    const float* __restrict__ hour_emb, const float* __restrict__ day_emb,
    const int* __restrict__ seq_lens, const int* __restrict__ ts_g,
    const float* __restrict__ g11, const float* __restrict__ b11,
    const float* __restrict__ wt1, const float* __restrict__ bf1,
    const float* __restrict__ wt2, const float* __restrict__ bf2,
    const float* __restrict__ g12, const float* __restrict__ b12,
    float* __restrict__ F)
{
  const int b = blockIdx.x >> 5;
  const int j0 = (blockIdx.x & 31) * 4;
  const int t = threadIdx.x, w = t >> 6, l = t & 63;
  const int colb = 4 * l;
  __shared__ float qs[4][DD];     // Q rows
  __shared__ float qhd[4][34];    // per-row emb dots
  __shared__ float whd[4][34];    // per-row weighted hist
  __shared__ int   tsl[LL];
  __shared__ float ss_t[LL][4];   // aw transposed [k][r]
  __shared__ float xs_t[DD][4];   // LN1 out transposed [e][r]
  __shared__ float hs_t[DD][4];   // relu out transposed [e][r]
  __shared__ float ps[4][4][DD];  // partials [wave][row][col]
  const int row0 = b * LL + j0;
  for (int i = t; i < 4 * DD; i += 256) qs[i >> 8][i & 255] = Q[row0 * DD + i];
  if (t < LL) tsl[t] = ts_g[b * LL + t];
  if (t < 136) (&whd[0][0])[t] = 0.f;
  __syncthreads();   // B1
  // ---- per-row embedding dots qhd[r][i] = Q[r] . emb_i ----
  if (t < 136) {
    const int r = t / 34, i = t - 34 * r;
    const float* ep = (i < 26) ? (hour_emb + i * DD) : (day_emb + (i - 26) * DD);
    float4 ac = {0.f,0.f,0.f,0.f};
    for (int e = 0; e < DD; e += 4) {
      const float4 q4 = *(const float4*)&qs[r][e];
      const float4 e4 = *(const float4*)(ep + e);
      ac.x += q4.x * e4.x; ac.y += q4.y * e4.y;
      ac.z += q4.z * e4.z; ac.w += q4.w * e4.w;
    }
    qhd[r][i] = (ac.x + ac.y) + (ac.z + ac.w);
  }
  __syncthreads();   // B2
  // ---- scores + softmax: wave w owns row j0+w; lane l owns k = 2l, 2l+1 ----
  const int len = seq_lens[b];
  const int jrow = j0 + w;
  {
    const float* ktb = KT + b * 32768;
    float2 kd0 = {0.f,0.f}, kd1 = {0.f,0.f}, kd2 = {0.f,0.f}, kd3 = {0.f,0.f};
    for (int e = 0; e < DD; e += 4) {
      const float4 q4 = *(const float4*)&qs[w][e];
      const float* kp = ktb + e * LL + 2 * l;
      const float2 c0 = *(const float2*)(kp);
      const float2 c1 = *(const float2*)(kp + LL);
      const float2 c2 = *(const float2*)(kp + 2 * LL);
      const float2 c3 = *(const float2*)(kp + 3 * LL);
      kd0.x += q4.x * c0.x; kd0.y += q4.x * c0.y;
      kd1.x += q4.y * c1.x; kd1.y += q4.y * c1.y;
      kd2.x += q4.z * c2.x; kd2.y += q4.z * c2.y;
      kd3.x += q4.w * c3.x; kd3.y += q4.w * c3.y;
    }
    const float kdot0 = (kd0.x + kd1.x) + (kd2.x + kd3.x);
    const float kdot1 = (kd0.y + kd1.y) + (kd2.y + kd3.y);
    const int k0i = 2 * l, k1i = 2 * l + 1;
    const int tj = tsl[jrow];
    int h0 = 0, d0 = 0, h1 = 0, d1 = 0;
    float s0 = NEGF, s1 = NEGF;
    if ((k0i <= jrow) && (jrow < len)) {
      const int df = tj - tsl[k0i];                     // >=0 (sorted, k<=j)
      h0 = (jrow == b) ? 1 : ((df % TU_C) / TB_C + 2);  // faithful j==b bug
      d0 = min(df / TU_C + 1, 7);
      s0 = (kdot0 + qhd[w][h0] + qhd[w][26 + d0]) * 0.0625f;
    }
    if ((k1i <= jrow) && (jrow < len)) {
      const int df = tj - tsl[k1i];
      h1 = (jrow == b) ? 1 : ((df % TU_C) / TB_C + 2);
      d1 = min(df / TU_C + 1, 7);
      s1 = (kdot1 + qhd[w][h1] + qhd[w][26 + d1]) * 0.0625f;
    }
    const float m = wredMax(fmaxf(s0, s1));   // all-NEG row -> uniform 1/128
    const float p0 = expf(s0 - m), p1 = expf(s1 - m);
    const float Z = wredSum(p0 + p1);
    const float aw0 = p0 / Z, aw1 = p1 / Z;
    ss_t[k0i][w] = aw0; ss_t[k1i][w] = aw1;
    atomicAdd(&whd[w][h0], aw0); atomicAdd(&whd[w][26 + d0], aw0);
    atomicAdd(&whd[w][h1], aw1); atomicAdd(&whd[w][26 + d1], aw1);
  }
  __syncthreads();   // B3
  // ---- aw@V partial: wave w = k-quarter, all 4 rows per V read ----
  {
    float4 a0 = {0.f,0.f,0.f,0.f}, a1 = {0.f,0.f,0.f,0.f};
    float4 a2 = {0.f,0.f,0.f,0.f}, a3 = {0.f,0.f,0.f,0.f};
    const int k0 = 32 * w;
    for (int k = k0; k < k0 + 32; ++k) {
      const float4 s4 = *(const float4*)&ss_t[k][0];
      const float4 v4 = *(const float4*)(Vm + (b * LL + k) * DD + colb);
      FMA4(a0, s4.x, v4) FMA4(a1, s4.y, v4) FMA4(a2, s4.z, v4) FMA4(a3, s4.w, v4)
    }
    *(float4*)&ps[w][0][colb] = a0;
    *(float4*)&ps[w][1][colb] = a1;
    *(float4*)&ps[w][2][colb] = a2;
    *(float4*)&ps[w][3][colb] = a3;
  }
  __syncthreads();   // B4
  // ---- x = combine + emb + src, LN1 (wave w = row w) ----
  {
    float4 x = *(const float4*)&ps[0][w][colb];
    ADD4(x, (*(const float4*)&ps[1][w][colb]))
    ADD4(x, (*(const float4*)&ps[2][w][colb]))
    ADD4(x, (*(const float4*)&ps[3][w][colb]))
#pragma unroll
    for (int i = 0; i < 26; ++i)
      FMA4(x, whd[w][i], *(const float4*)(hour_emb + i * DD + colb))
#pragma unroll
    for (int i = 0; i < 8; ++i)
      FMA4(x, whd[w][26 + i], *(const float4*)(day_emb + i * DD + colb))
    const float4 s4 = *(const float4*)(src + (row0 + w) * DD + colb);
    ADD4(x, s4)
    const float sm = wredSum(x.x + x.y + x.z + x.w);
    const float sq = wredSum(x.x*x.x + x.y*x.y + x.z*x.z + x.w*x.w);
    const float mean = sm * (1.f / DD);
    const float rstd = rsqrtf(sq * (1.f / DD) - mean * mean + 1e-5f);
    const float4 g4 = *(const float4*)(g11 + colb);
    const float4 b4 = *(const float4*)(b11 + colb);
    xs_t[colb + 0][w] = (x.x - mean) * rstd * g4.x + b4.x;
    xs_t[colb + 1][w] = (x.y - mean) * rstd * g4.y + b4.y;
    xs_t[colb + 2][w] = (x.z - mean) * rstd * g4.z + b4.z;
    xs_t[colb + 3][w] = (x.w - mean) * rstd * g4.w + b4.w;
  }
  __syncthreads();   // B5
  // ---- FFN1 partial: wave w = e-quarter, 4 rows per weight read ----
  {
    float4 a0 = {0.f,0.f,0.f,0.f}, a1 = {0.f,0.f,0.f,0.f};
    float4 a2 = {0.f,0.f,0.f,0.f}, a3 = {0.f,0.f,0.f,0.f};
    const int e0 = 64 * w;
    for (int e = e0; e < e0 + 64; ++e) {
      const float4 x4 = *(const float4*)&xs_t[e][0];
      const float4 w4 = *(const float4*)(wt1 + e * DD + colb);
      FMA4(a0, x4.x, w4) FMA4(a1, x4.y, w4) FMA4(a2, x4.z, w4) FMA4(a3, x4.w, w4)
    }
    *(float4*)&ps[w][0][colb] = a0;
    *(float4*)&ps[w][1][colb] = a1;
    *(float4*)&ps[w][2][colb] = a2;
    *(float4*)&ps[w][3][colb] = a3;
  }
  __syncthreads();   // B6
  // ---- combine1 + bias + relu (wave w = row w) ----
  {
    float4 h = *(const float4*)(bf1 + colb);
    ADD4(h, (*(const float4*)&ps[0][w][colb]))
    ADD4(h, (*(const float4*)&ps[1][w][colb]))
    ADD4(h, (*(const float4*)&ps[2][w][colb]))
    ADD4(h, (*(const float4*)&ps[3][w][colb]))
    hs_t[colb + 0][w] = fmaxf(h.x, 0.f);
    hs_t[colb + 1][w] = fmaxf(h.y, 0.f);
    hs_t[colb + 2][w] = fmaxf(h.z, 0.f);
    hs_t[colb + 3][w] = fmaxf(h.w, 0.f);
  }
  __syncthreads();   // B7
  // ---- FFN2 partial ----
  {
    float4 a0 = {0.f,0.f,0.f,0.f}, a1 = {0.f,0.f,0.f,0.f};
    float4 a2 = {0.f,0.f,0.f,0.f}, a3 = {0.f,0.f,0.f,0.f};
    const int e0 = 64 * w;
    for (int e = e0; e < e0 + 64; ++e) {
      const float4 h4 = *(const float4*)&hs_t[e][0];
      const float4 w4 = *(const float4*)(wt2 + e * DD + colb);
      FMA4(a0, h4.x, w4) FMA4(a1, h4.y, w4) FMA4(a2, h4.z, w4) FMA4(a3, h4.w, w4)
    }
    *(float4*)&ps[w][0][colb] = a0;
    *(float4*)&ps[w][1][colb] = a1;
    *(float4*)&ps[w][2][colb] = a2;
    *(float4*)&ps[w][3][colb] = a3;
  }
  __syncthreads();   // B8
  // ---- combine2 + bias + residual + LN2 + store (wave w = row w) ----
  {
    float4 o = *(const float4*)(bf2 + colb);
    ADD4(o, (*(const float4*)&ps[0][w][colb]))
    ADD4(o, (*(const float4*)&ps[1][w][colb]))
    ADD4(o, (*(const float4*)&ps[2][w][colb]))
    ADD4(o, (*(const float4*)&ps[3][w][colb]))
    o.x += xs_t[colb + 0][w]; o.y += xs_t[colb + 1][w];
    o.z += xs_t[colb + 2][w]; o.w += xs_t[colb + 3][w];
    const float sm = wredSum(o.x + o.y + o.z + o.w);
    const float sq = wredSum(o.x*o.x + o.y*o.y + o.z*o.z + o.w*o.w);
    const float mean = sm * (1.f / DD);
    const float rstd = rsqrtf(sq * (1.f / DD) - mean * mean + 1e-5f);
    const float4 g4 = *(const float4*)(g12 + colb);
    const float4 b4 = *(const float4*)(b12 + colb);
    o.x = (o.x - mean) * rstd * g4.x + b4.x;
    o.y = (o.y - mean) * rstd * g4.y + b4.y;
    o.z = (o.z - mean) * rstd * g4.z + b4.z;
    o.w = (o.w - mean) * rstd * g4.w + b4.w;
    *(float4*)(F + (row0 + w) * DD + colb) = o;
  }
}

// ---------------------------------------------------------------------------
// Kernel 3: FUSED prep + decoder GEMM. grid (4 col-tiles of 256, 64 row-tiles
// of 8), 256 thr. Phase A: GS rows in LDS (prefix over F + label-emb hist).
// Phase B: GEMM vs WTdec (coalesced 1KB weight lines shared by 8 rows).
// ---------------------------------------------------------------------------
__global__ __launch_bounds__(256) void k_decf(
    const float* __restrict__ F,
    const float* __restrict__ hour_emb, const float* __restrict__ day_emb,
    const int* __restrict__ seq_lens, const int* __restrict__ ts_g,
    const int* __restrict__ lts_g,
    const float* __restrict__ wtd, const float* __restrict__ bdec,
    float* __restrict__ out)
{
  const int c0 = blockIdx.x * 256;
  const int r0g = blockIdx.y * 8;
  const int b = r0g >> 7, j0 = r0g & 127;
  const int t = threadIdx.x;
  __shared__ float xs[8][DD];
  __shared__ float cnt[8][34];
  for (int i = t; i < 8 * 34; i += 256) (&cnt[0][0])[i] = 0.f;
  __syncthreads();
  const int len = seq_lens[b];
  const int* ts = ts_g + b * LL;
  const int* lts = lts_g + b * LL;
#pragma unroll
  for (int p = 0; p < 4; ++p) {
    const int idx = p * 256 + t;
    const int jj = idx >> 7, k = idx & 127, j = j0 + jj;
    if (k <= j && j < len) {           // valid; no j==b override for labels
      const int ld = lts[j] - ts[k];   // >= 0
      atomicAdd(&cnt[jj][(ld % TU_C) / TB_C + 2], 1.f);
      atomicAdd(&cnt[jj][26 + min(ld / TU_C + 1, 7)], 1.f);
    }
  }
  __syncthreads();
  {
    float he[26], de[8];
#pragma unroll
    for (int i = 0; i < 26; ++i) he[i] = hour_emb[i * DD + t];
#pragma unroll
    for (int i = 0; i < 8; ++i)  de[i] = day_emb[i * DD + t];
    const float* fb = F + b * LL * DD + t;
    float A0 = 0.f, A1 = 0.f, A2 = 0.f, A3 = 0.f;
    for (int k = 0; k < j0; k += 4) {   // j0 multiple of 8
      A0 += fb[(k + 0) * DD]; A1 += fb[(k + 1) * DD];
      A2 += fb[(k + 2) * DD]; A3 += fb[(k + 3) * DD];
    }
    float gacc = (A0 + A1) + (A2 + A3);
#pragma unroll
    for (int jj = 0; jj < 8; ++jj) {
      gacc += fb[(j0 + jj) * DD];       // pooling sums ALL k<=j
      float s0 = 0.f, s1 = 0.f;
#pragma unroll
      for (int i = 0; i < 26; i += 2) {
        s0 += cnt[jj][i] * he[i]; s1 += cnt[jj][i + 1] * he[i + 1];
      }
#pragma unroll
      for (int i = 0; i < 8; i += 2) {
        s0 += cnt[jj][26 + i] * de[i]; s1 += cnt[jj][27 + i] * de[i + 1];
      }
      xs[jj][t] = (gacc + s0 + s1) / (float)(j0 + jj + 1);
    }
  }
  __syncthreads();
  const int cg = t & 63, rg = t >> 6;
  const int col = c0 + 4 * cg, rA = 2 * rg, rB = rA + 1;
  const float4 b4 = *(const float4*)(bdec + col);
  float4 a0 = b4, a1 = b4;
  for (int e = 0; e < DD; ++e) {
    const float4 w4 = *(const float4*)(wtd + e * PP + col);
    FMA4(a0, xs[rA][e], w4)
    FMA4(a1, xs[rB][e], w4)
  }
  *(float4*)(out + (r0g + rA) * PP + col) = a0;
  *(float4*)(out + (r0g + rB) * PP + col) = a1;
}

extern "C" void kernel_launch(void* const* d_in, const int* in_sizes, int n_in,
                              void* d_out, int out_size, void* d_ws, size_t ws_size,
                              hipStream_t stream)
{
  (void)in_sizes; (void)n_in; (void)out_size; (void)ws_size;
  const float* src      = (const float*)d_in[0];
  const float* hour_emb = (const float*)d_in[1];
  const float* day_emb  = (const float*)d_in[2];
  const float* wq  = (const float*)d_in[3];
  const float* bq  = (const float*)d_in[4];
  const float* wk  = (const float*)d_in[5];
  const float* bk  = (const float*)d_in[6];
  const float* wv  = (const float*)d_in[7];
  const float* bv  = (const float*)d_in[8];
  const float* g11 = (const float*)d_in[9];
  const float* b11 = (const float*)d_in[10];
  const float* wf1 = (const float*)d_in[11];
  const float* bf1 = (const float*)d_in[12];
  const float* wf2 = (const float*)d_in[13];
  const float* bf2 = (const float*)d_in[14];
  const float* g12 = (const float*)d_in[15];
  const float* b12 = (const float*)d_in[16];
  const float* wdec = (const float*)d_in[17];
  const float* bdec = (const float*)d_in[18];
  const int* seq_lens = (const int*)d_in[19];
  const int* ts  = (const int*)d_in[20];
  const int* lts = (const int*)d_in[21];
  float* out = (float*)d_out;
  float* ws = (float*)d_ws;
  // ws layout (floats):
  float* WT = ws;                  // 589824 (5x65536 + 262144)
  float* Q  = ws + 589824;         // 131072
  float* KT = ws + 720896;         // 131072 (4 x [256e][128k])
  float* V  = ws + 851968;         // 131072
  float* F  = ws + 983040;         // 131072

  k_wt  <<<576, 256, 0, stream>>>(wq, wk, wv, wf1, wf2, wdec, WT);
  k_qkv <<<dim3(64, 3), 512, 0, stream>>>(src, WT, bq, bk, bv, Q, KT, V);
  k_attn<<<128, 256, 0, stream>>>(Q, KT, V, src, hour_emb, day_emb, seq_lens, ts,
                                  g11, b11, WT + 196608, bf1, WT + 262144, bf2,
                                  g12, b12, F);
  k_decf<<<dim3(4, 64), 256, 0, stream>>>(F, hour_emb, day_emb, seq_lens, ts, lts,
                                          WT + 327680, bdec, out);
}

// Round 10
// 69.765 us; speedup vs baseline: 1.2379x; 1.1738x over previous
//
#include <hip/hip_runtime.h>
#include <hip/hip_bf16.h>

#define LL 128
#define DD 256
#define PP 1024
#define TU_C 86400
#define TB_C 3600
#define NEGF -4294967296.0f   // float(-2**32+1) rounds to -2^32

// NOTE: parameter names must not collide with .x/.y/.z/.w member tokens
#define FMA4(ACC_, SS_, WW_) { (ACC_).x += (SS_)*(WW_).x; (ACC_).y += (SS_)*(WW_).y; (ACC_).z += (SS_)*(WW_).z; (ACC_).w += (SS_)*(WW_).w; }
#define ADD4(ACC_, WW_) { (ACC_).x += (WW_).x; (ACC_).y += (WW_).y; (ACC_).z += (WW_).z; (ACC_).w += (WW_).w; }

__device__ __forceinline__ float wredSum(float v) {
#pragma unroll
  for (int o = 32; o; o >>= 1) v += __shfl_xor(v, o);
  return v;
}
__device__ __forceinline__ float wredMax(float v) {
#pragma unroll
  for (int o = 32; o; o >>= 1) v = fmaxf(v, __shfl_xor(v, o));
  return v;
}

// ---------------------------------------------------------------------------
// Kernel 0: transpose weights. WT: WTq 0, WTk 65536, WTv 131072, WTf1 196608,
// WTf2 262144, WTdec 327680. 32x32 tiles, 576 blocks. (proven)
// ---------------------------------------------------------------------------
__global__ __launch_bounds__(256) void k_wt(
    const float* __restrict__ wq, const float* __restrict__ wk,
    const float* __restrict__ wv, const float* __restrict__ wf1,
    const float* __restrict__ wf2, const float* __restrict__ wdec,
    float* __restrict__ wt)
{
  __shared__ float s[32][33];
  const int tile = blockIdx.x;
  const float* src; float* dst; int R, m;
  if (tile < 320) {
    const int mi = tile >> 6; m = tile & 63;
    src = (mi == 0) ? wq : (mi == 1) ? wk : (mi == 2) ? wv : (mi == 3) ? wf1 : wf2;
    dst = wt + mi * 65536; R = 256;
  } else {
    m = tile - 320; src = wdec; dst = wt + 327680; R = 1024;
  }
  const int sr = (m >> 3) * 32, sc0 = (m & 7) * 32;
  const int tx = threadIdx.x & 31, ty = threadIdx.x >> 5;
#pragma unroll
  for (int i = 0; i < 4; ++i)
    s[ty + 8 * i][tx] = src[(sr + ty + 8 * i) * 256 + sc0 + tx];
  __syncthreads();
#pragma unroll
  for (int i = 0; i < 4; ++i)
    dst[(sc0 + ty + 8 * i) * R + sr + tx] = s[tx][ty + 8 * i];
}

// ---------------------------------------------------------------------------
// Kernel 1: Q/K/V projections. grid (64,3), 512 thr. (proven)
// K written TRANSPOSED per batch: KT[b][e][k].
// ---------------------------------------------------------------------------
__global__ __launch_bounds__(512) void k_qkv(
    const float* __restrict__ src, const float* __restrict__ wt,
    const float* __restrict__ bq, const float* __restrict__ bk,
    const float* __restrict__ bv,
    float* __restrict__ Q, float* __restrict__ KT, float* __restrict__ V)
{
  __shared__ float xs[8][DD];
  const int t = threadIdx.x, cg = t & 63, rg = t >> 6;
  const int r0 = blockIdx.x * 8;
  const int mat = blockIdx.y;
  const float* w = wt + mat * 65536;
  const float* bi = (mat == 0) ? bq : (mat == 1) ? bk : bv;
  for (int i = t; i < 8 * DD; i += 512) xs[i >> 8][i & 255] = src[r0 * DD + i];
  __syncthreads();
  float4 a0 = *(const float4*)(bi + 4 * cg);
  float4 a1 = {0.f,0.f,0.f,0.f}, a2 = {0.f,0.f,0.f,0.f}, a3 = {0.f,0.f,0.f,0.f};
  for (int e = 0; e < DD; e += 4) {
    const float4 xa = *(const float4*)&xs[rg][e];
    const float* wp = w + e * DD + 4 * cg;
    FMA4(a0, xa.x, *(const float4*)(wp))
    FMA4(a1, xa.y, *(const float4*)(wp + DD))
    FMA4(a2, xa.z, *(const float4*)(wp + 2 * DD))
    FMA4(a3, xa.w, *(const float4*)(wp + 3 * DD))
  }
  a0.x = (a0.x + a1.x) + (a2.x + a3.x);
  a0.y = (a0.y + a1.y) + (a2.y + a3.y);
  a0.z = (a0.z + a1.z) + (a2.z + a3.z);
  a0.w = (a0.w + a1.w) + (a2.w + a3.w);
  const int r = r0 + rg;
  if (mat == 1) {
    const int bA = r >> 7, kA = r & 127;
    KT[bA * 32768 + (4 * cg + 0) * 128 + kA] = a0.x;
    KT[bA * 32768 + (4 * cg + 1) * 128 + kA] = a0.y;
    KT[bA * 32768 + (4 * cg + 2) * 128 + kA] = a0.z;
    KT[bA * 32768 + (4 * cg + 3) * 128 + kA] = a0.w;
  } else {
    float* o = (mat == 0) ? Q : V;
    *(float4*)(o + r * DD + 4 * cg) = a0;
  }
}

// ---------------------------------------------------------------------------
// Kernel 2: attention scores+softmax+weighted hist. grid 512=(b,j), 192 thr.
// (round-7 proven structure)
// ---------------------------------------------------------------------------
__global__ __launch_bounds__(192) void k_attnA(
    const float* __restrict__ Q, const float* __restrict__ KT,
    const float* __restrict__ hour_emb, const float* __restrict__ day_emb,
    const int* __restrict__ seq_lens, const int* __restrict__ ts_g,
    float* __restrict__ Sout, float* __restrict__ WHout)
{
  const int b = blockIdx.x >> 7;
  const int j = blockIdx.x & (LL - 1);
  const int t = threadIdx.x;
  __shared__ float qrow[DD];
  __shared__ float qhd[34];
  __shared__ float whd[34];
  __shared__ float red[8];
  const int row = b * LL + j;
  for (int i = t; i < DD; i += 192) qrow[i] = Q[row * DD + i];
  if (t < 34) whd[t] = 0.f;
  __syncthreads();
  float kdot = 0.f;
  if (t < LL) {
    const float* ktb = KT + b * 32768;
    float4 kd = {0.f,0.f,0.f,0.f};
#pragma unroll 8
    for (int e = 0; e < DD; e += 4) {
      const float4 q4 = *(const float4*)&qrow[e];
      const float* kp = ktb + e * LL + t;
      kd.x += q4.x * kp[0];
      kd.y += q4.y * kp[128];
      kd.z += q4.z * kp[256];
      kd.w += q4.w * kp[384];
    }
    kdot = (kd.x + kd.y) + (kd.z + kd.w);
  } else if (t < 162) {
    const int i = t - 128;
    const float* emb = (i < 26) ? (hour_emb + i * DD) : (day_emb + (i - 26) * DD);
    float4 ed = {0.f,0.f,0.f,0.f};
    for (int e = 0; e < DD; e += 4) {
      const float4 q4 = *(const float4*)&qrow[e];
      const float4 e4 = *(const float4*)(emb + e);
      ed.x += q4.x * e4.x; ed.y += q4.y * e4.y;
      ed.z += q4.z * e4.z; ed.w += q4.w * e4.w;
    }
    qhd[i] = (ed.x + ed.y) + (ed.z + ed.w);
  }
  const int len = seq_lens[b];
  const int* ts = ts_g + b * LL;
  const int tj = ts[j];
  __syncthreads();  // qhd ready
  int hidx = 0, didx = 0;
  float s = NEGF;
  const bool valid = (t < LL) && (j < len) && (t <= j);
  if (valid) {
    const int diff = tj - ts[t];                       // >= 0 (ts sorted, t<=j)
    hidx = (j == b) ? 1 : ((diff % TU_C) / TB_C + 2);  // faithful j==b bug
    didx = min(diff / TU_C + 1, 7);
    s = (kdot + qhd[hidx] + qhd[26 + didx]) * 0.0625f; // /sqrt(256)
  }
  // softmax over k=0..127 (all-NEG rows -> uniform 1/128, like reference)
  float mv = (t < LL) ? s : -3.4e38f;
  mv = wredMax(mv);
  if ((t & 63) == 0) red[t >> 6] = mv;
  __syncthreads();
  const float m = fmaxf(red[0], red[1]);
  const float p = (t < LL) ? expf(s - m) : 0.f;
  const float sv = wredSum(p);
  if ((t & 63) == 0) red[4 + (t >> 6)] = sv;
  __syncthreads();
  const float Z = red[4] + red[5];
  if (t < LL) {
    const float aw = p / Z;
    Sout[row * LL + t] = aw;
    atomicAdd(&whd[hidx], aw);       // idx 0 -> zero embedding row: harmless
    atomicAdd(&whd[26 + didx], aw);
  }
  __syncthreads();
  if (t < 34) WHout[row * 34 + t] = whd[t];
}

// ---------------------------------------------------------------------------
// Kernel 3: fused (aw@V + emb + residual + LN1) + FFN + LN2 -> F.
// grid 256 = (b, 64 row-pairs), 512 threads = 8 waves.
// Every reduction dim split across 8 waves; both rows share each weight/V
// line (read once per block). x/h operands via LDS broadcast.
// ---------------------------------------------------------------------------
__global__ __launch_bounds__(512) void k_ffnf(
    const float* __restrict__ Sin, const float* __restrict__ WHin,
    const float* __restrict__ Vm, const float* __restrict__ src,
    const float* __restrict__ hour_emb, const float* __restrict__ day_emb,
    const float* __restrict__ g11, const float* __restrict__ b11,
    const float* __restrict__ wt1, const float* __restrict__ bf1,
    const float* __restrict__ wt2, const float* __restrict__ bf2,
    const float* __restrict__ g12, const float* __restrict__ b12,
    float* __restrict__ F)
{
  const int b = blockIdx.x >> 6;
  const int j0 = (blockIdx.x & 63) * 2;
  const int t = threadIdx.x, w = t >> 6, l = t & 63;
  const int col = 4 * l;
  __shared__ float ss[2][LL];
  __shared__ float wh2[2][34];
  __shared__ float xs2[2][DD];
  __shared__ float hs2[2][DD];
  __shared__ float ps[8][2][DD];
  const int row0 = b * LL + j0;
  if (t < 256) ss[t >> 7][t & 127] = Sin[row0 * LL + t];
  else if (t < 256 + 68) {
    const int i = t - 256;
    wh2[i / 34][i % 34] = WHin[row0 * 34 + i];
  }
  __syncthreads();   // B1
  // ---- Phase 1: aw@V k-slice (16 k's per wave), both rows ----
  {
    float4 a0 = {0.f,0.f,0.f,0.f}, a1 = {0.f,0.f,0.f,0.f};
    const float* vb = Vm + b * LL * DD + col;
    const int k0 = 16 * w;
#pragma unroll
    for (int kk = 0; kk < 16; ++kk) {
      const int k = k0 + kk;
      const float4 v4 = *(const float4*)(vb + k * DD);
      FMA4(a0, ss[0][k], v4)
      FMA4(a1, ss[1][k], v4)
    }
    if (w == 0) {
#pragma unroll
      for (int i = 0; i < 26; ++i)
        FMA4(a0, wh2[0][i], *(const float4*)(hour_emb + i * DD + col))
    } else if (w == 1) {
#pragma unroll
      for (int i = 0; i < 26; ++i)
        FMA4(a1, wh2[1][i], *(const float4*)(hour_emb + i * DD + col))
    } else if (w == 2) {
#pragma unroll
      for (int i = 0; i < 8; ++i)
        FMA4(a0, wh2[0][26 + i], *(const float4*)(day_emb + i * DD + col))
      const float4 s4 = *(const float4*)(src + row0 * DD + col);
      ADD4(a0, s4)
    } else if (w == 3) {
#pragma unroll
      for (int i = 0; i < 8; ++i)
        FMA4(a1, wh2[1][26 + i], *(const float4*)(day_emb + i * DD + col))
      const float4 s4 = *(const float4*)(src + (row0 + 1) * DD + col);
      ADD4(a1, s4)
    }
    *(float4*)&ps[w][0][col] = a0;
    *(float4*)&ps[w][1][col] = a1;
  }
  __syncthreads();   // B2
  if (w < 2) {   // combine + LN1 (wave w = row w)
    float4 x = *(const float4*)&ps[0][w][col];
#pragma unroll
    for (int i = 1; i < 8; ++i) ADD4(x, (*(const float4*)&ps[i][w][col]))
    const float sm = wredSum(x.x + x.y + x.z + x.w);
    const float sq = wredSum(x.x*x.x + x.y*x.y + x.z*x.z + x.w*x.w);
    const float mean = sm * (1.f / DD);
    const float rstd = rsqrtf(sq * (1.f / DD) - mean * mean + 1e-5f);
    const float4 g4 = *(const float4*)(g11 + col);
    const float4 b4 = *(const float4*)(b11 + col);
    x.x = (x.x - mean) * rstd * g4.x + b4.x;
    x.y = (x.y - mean) * rstd * g4.y + b4.y;
    x.z = (x.z - mean) * rstd * g4.z + b4.z;
    x.w = (x.w - mean) * rstd * g4.w + b4.w;
    *(float4*)&xs2[w][col] = x;
  }
  __syncthreads();   // B3
  // ---- Phase 2: FFN1 e-slice (32 e's per wave), both rows per weight ----
  {
    float4 a0 = {0.f,0.f,0.f,0.f}, a1 = {0.f,0.f,0.f,0.f};
    const int e0 = 32 * w;
#pragma unroll 8
    for (int ee = 0; ee < 32; ++ee) {
      const int e = e0 + ee;
      const float4 w4 = *(const float4*)(wt1 + e * DD + col);
      FMA4(a0, xs2[0][e], w4)
      FMA4(a1, xs2[1][e], w4)
    }
    *(float4*)&ps[w][0][col] = a0;
    *(float4*)&ps[w][1][col] = a1;
  }
  __syncthreads();   // B4
  if (w < 2) {   // combine + bias + relu
    float4 h = *(const float4*)(bf1 + col);
#pragma unroll
    for (int i = 0; i < 8; ++i) ADD4(h, (*(const float4*)&ps[i][w][col]))
    h.x = fmaxf(h.x, 0.f); h.y = fmaxf(h.y, 0.f);
    h.z = fmaxf(h.z, 0.f); h.w = fmaxf(h.w, 0.f);
    *(float4*)&hs2[w][col] = h;
  }
  __syncthreads();   // B5
  // ---- Phase 3: FFN2 e-slice ----
  {
    float4 a0 = {0.f,0.f,0.f,0.f}, a1 = {0.f,0.f,0.f,0.f};
    const int e0 = 32 * w;
#pragma unroll 8
    for (int ee = 0; ee < 32; ++ee) {
      const int e = e0 + ee;
      const float4 w4 = *(const float4*)(wt2 + e * DD + col);
      FMA4(a0, hs2[0][e], w4)
      FMA4(a1, hs2[1][e], w4)
    }
    *(float4*)&ps[w][0][col] = a0;
    *(float4*)&ps[w][1][col] = a1;
  }
  __syncthreads();   // B6
  if (w < 2) {   // combine + bias + residual + LN2 + store
    float4 o = *(const float4*)(bf2 + col);
#pragma unroll
    for (int i = 0; i < 8; ++i) ADD4(o, (*(const float4*)&ps[i][w][col]))
    const float4 xr = *(const float4*)&xs2[w][col];
    ADD4(o, xr)
    const float sm = wredSum(o.x + o.y + o.z + o.w);
    const float sq = wredSum(o.x*o.x + o.y*o.y + o.z*o.z + o.w*o.w);
    const float mean = sm * (1.f / DD);
    const float rstd = rsqrtf(sq * (1.f / DD) - mean * mean + 1e-5f);
    const float4 g4 = *(const float4*)(g12 + col);
    const float4 b4 = *(const float4*)(b12 + col);
    o.x = (o.x - mean) * rstd * g4.x + b4.x;
    o.y = (o.y - mean) * rstd * g4.y + b4.y;
    o.z = (o.z - mean) * rstd * g4.z + b4.z;
    o.w = (o.w - mean) * rstd * g4.w + b4.w;
    *(float4*)(F + (row0 + w) * DD + col) = o;
  }
}

// ---------------------------------------------------------------------------
// Kernel 4: FUSED prep + decoder GEMM. grid (4 col-tiles of 256, 64 row-tiles
// of 8), 256 thr. Phase A: GS rows in LDS (prefix over F + label-emb hist).
// Phase B: GEMM vs WTdec (1KB coalesced weight lines shared by 8 rows).
// ---------------------------------------------------------------------------
__global__ __launch_bounds__(256) void k_decf(
    const float* __restrict__ F,
    const float* __restrict__ hour_emb, const float* __restrict__ day_emb,
    const int* __restrict__ seq_lens, const int* __restrict__ ts_g,
    const int* __restrict__ lts_g,
    const float* __restrict__ wtd, const float* __restrict__ bdec,
    float* __restrict__ out)
{
  const int c0 = blockIdx.x * 256;
  const int r0g = blockIdx.y * 8;
  const int b = r0g >> 7, j0 = r0g & 127;
  const int t = threadIdx.x;
  __shared__ float xs[8][DD];
  __shared__ float cnt[8][34];
  for (int i = t; i < 8 * 34; i += 256) (&cnt[0][0])[i] = 0.f;
  __syncthreads();
  const int len = seq_lens[b];
  const int* ts = ts_g + b * LL;
  const int* lts = lts_g + b * LL;
#pragma unroll
  for (int p = 0; p < 4; ++p) {
    const int idx = p * 256 + t;
    const int jj = idx >> 7, k = idx & 127, j = j0 + jj;
    if (k <= j && j < len) {           // valid; no j==b override for labels
      const int ld = lts[j] - ts[k];   // >= 0
      atomicAdd(&cnt[jj][(ld % TU_C) / TB_C + 2], 1.f);
      atomicAdd(&cnt[jj][26 + min(ld / TU_C + 1, 7)], 1.f);
    }
  }
  __syncthreads();
  {
    float he[26], de[8];
#pragma unroll
    for (int i = 0; i < 26; ++i) he[i] = hour_emb[i * DD + t];
#pragma unroll
    for (int i = 0; i < 8; ++i)  de[i] = day_emb[i * DD + t];
    const float* fb = F + b * LL * DD + t;
    float A0 = 0.f, A1 = 0.f, A2 = 0.f, A3 = 0.f;
#pragma unroll 4
    for (int k = 0; k < j0; k += 4) {   // j0 multiple of 8
      A0 += fb[(k + 0) * DD]; A1 += fb[(k + 1) * DD];
      A2 += fb[(k + 2) * DD]; A3 += fb[(k + 3) * DD];
    }
    float gacc = (A0 + A1) + (A2 + A3);
#pragma unroll
    for (int jj = 0; jj < 8; ++jj) {
      gacc += fb[(j0 + jj) * DD];       // pooling sums ALL k<=j
      float s0 = 0.f, s1 = 0.f;
#pragma unroll
      for (int i = 0; i < 26; i += 2) {
        s0 += cnt[jj][i] * he[i]; s1 += cnt[jj][i + 1] * he[i + 1];
      }
#pragma unroll
      for (int i = 0; i < 8; i += 2) {
        s0 += cnt[jj][26 + i] * de[i]; s1 += cnt[jj][27 + i] * de[i + 1];
      }
      xs[jj][t] = (gacc + s0 + s1) / (float)(j0 + jj + 1);
    }
  }
  __syncthreads();
  const int cg = t & 63, rg = t >> 6;
  const int col = c0 + 4 * cg, rA = 2 * rg, rB = rA + 1;
  const float4 b4 = *(const float4*)(bdec + col);
  float4 a0 = b4, a1 = b4;
#pragma unroll 8
  for (int e = 0; e < DD; ++e) {
    const float4 w4 = *(const float4*)(wtd + e * PP + col);
    FMA4(a0, xs[rA][e], w4)
    FMA4(a1, xs[rB][e], w4)
  }
  *(float4*)(out + (r0g + rA) * PP + col) = a0;
  *(float4*)(out + (r0g + rB) * PP + col) = a1;
}

extern "C" void kernel_launch(void* const* d_in, const int* in_sizes, int n_in,
                              void* d_out, int out_size, void* d_ws, size_t ws_size,
                              hipStream_t stream)
{
  (void)in_sizes; (void)n_in; (void)out_size; (void)ws_size;
  const float* src      = (const float*)d_in[0];
  const float* hour_emb = (const float*)d_in[1];
  const float* day_emb  = (const float*)d_in[2];
  const float* wq  = (const float*)d_in[3];
  const float* bq  = (const float*)d_in[4];
  const float* wk  = (const float*)d_in[5];
  const float* bk  = (const float*)d_in[6];
  const float* wv  = (const float*)d_in[7];
  const float* bv  = (const float*)d_in[8];
  const float* g11 = (const float*)d_in[9];
  const float* b11 = (const float*)d_in[10];
  const float* wf1 = (const float*)d_in[11];
  const float* bf1 = (const float*)d_in[12];
  const float* wf2 = (const float*)d_in[13];
  const float* bf2 = (const float*)d_in[14];
  const float* g12 = (const float*)d_in[15];
  const float* b12 = (const float*)d_in[16];
  const float* wdec = (const float*)d_in[17];
  const float* bdec = (const float*)d_in[18];
  const int* seq_lens = (const int*)d_in[19];
  const int* ts  = (const int*)d_in[20];
  const int* lts = (const int*)d_in[21];
  float* out = (float*)d_out;
  float* ws = (float*)d_ws;
  // ws layout (floats):
  float* WT = ws;                  // 589824 (5x65536 + 262144)
  float* Q  = ws + 589824;         // 131072
  float* KT = ws + 720896;         // 131072 (4 x [256e][128k])
  float* V  = ws + 851968;         // 131072
  float* F  = ws + 983040;         // 131072
  float* S  = ws + 1114112;        // 65536  (512 x 128 attention rows)
  float* WH = ws + 1179648;        // 17408  (512 x 34 weighted hists)

  k_wt   <<<576, 256, 0, stream>>>(wq, wk, wv, wf1, wf2, wdec, WT);
  k_qkv  <<<dim3(64, 3), 512, 0, stream>>>(src, WT, bq, bk, bv, Q, KT, V);
  k_attnA<<<512, 192, 0, stream>>>(Q, KT, hour_emb, day_emb, seq_lens, ts, S, WH);
  k_ffnf <<<256, 512, 0, stream>>>(S, WH, V, src, hour_emb, day_emb, g11, b11,
                                   WT + 196608, bf1, WT + 262144, bf2, g12, b12, F);
  k_decf <<<dim3(4, 64), 256, 0, stream>>>(F, hour_emb, day_emb, seq_lens, ts, lts,
                                           WT + 327680, bdec, out);
}